// Round 12
// baseline (33.381 us; speedup 1.0000x reference)
//
#include <hip/hip_runtime.h>
#include <math.h>

// ---------------------------------------------------------------------------
// DirectVoxGO Raw2Alpha + Alphas2Weights (forward), single fused kernel.
//
// outputs (concatenated in d_out, float32):
//   weights[n_pts]         = alpha_j * T_j,  T_j = prod_{k<j} (1-alpha_k)
//   alphainv_last[n_rays]  = prod over ray of (1-alpha)  (empty rays -> 1.0)
//
// Structure: 1 block (256 thr) per 4096 consecutive points, 16 pts/thread.
// XCD-aware bijective block swizzle so data-neighbor blocks share an XCD's
// L2 -> the 256-point lookback window (to recompute the straddling ray's
// head product) is an L2 hit. All loads issued up front; 2 barriers/block.
// Segmented multiplicative scan: thread-local fold -> wave64 DPP (value,
// flag) scan -> 4-wave LDS combine -> local head-carry fold.
// ---------------------------------------------------------------------------

#define LOG2E 1.4426950408889634f
#define EPT   16                    // elements per thread
#define BPTS  (256 * EPT)           // points per block = 4096
#define NXCD  8

typedef float vf4 __attribute__((ext_vector_type(4)));

__device__ __forceinline__ float exp2f_(float x) { return __builtin_amdgcn_exp2f(x); }
__device__ __forceinline__ float log2f_(float x) { return __builtin_amdgcn_logf(x); }
__device__ __forceinline__ float rsqf_(float x)  { return __builtin_amdgcn_rsqf(x); }

__device__ __forceinline__ float oma(float d, float sh2, float negc, bool fast) {
    const float y = fmaf(d, LOG2E, sh2);
    if (fast) return rsqf_(1.0f + exp2f_(y));
    const float sp = fmaxf(y, 0.f) + log2f_(1.f + exp2f_(-fabsf(y)));
    return exp2f_(negc * sp);
}

// Segmented-scan DPP step: combine src (earlier lanes, identity (1,0) when
// out-of-row/masked) into (V,F):  V = F ? V : Vs*V;  F |= Fs.
template <int CTRL, int RM>
__device__ __forceinline__ void seg_step(float& V, int& F) {
    const int vs_i = __builtin_amdgcn_update_dpp(
        0x3f800000, __builtin_bit_cast(int, V), CTRL, RM, 0xF, false);
    const int fs = __builtin_amdgcn_update_dpp(0, F, CTRL, RM, 0xF, false);
    const float vs = __builtin_bit_cast(float, vs_i);
    V = F ? V : vs * V;
    F = F | fs;
}

// Full-wave product, result broadcast to all lanes.
__device__ __forceinline__ float wave_prod_bcast(float x) {
#define STEPP(CTRL, RM)                                                        \
    { int t_ = __builtin_amdgcn_update_dpp(0x3f800000,                         \
          __builtin_bit_cast(int, x), CTRL, RM, 0xF, false);                   \
      x *= __builtin_bit_cast(float, t_); }
    STEPP(0x111, 0xF) STEPP(0x112, 0xF) STEPP(0x114, 0xF)
    STEPP(0x118, 0xF) STEPP(0x142, 0xA) STEPP(0x143, 0xC)
#undef STEPP
    return __builtin_bit_cast(float,
        __builtin_amdgcn_readlane(__builtin_bit_cast(int, x), 63));
}

// Full-wave int max, result broadcast to all lanes.
__device__ __forceinline__ int wave_imax_bcast(int x) {
#define STEPM(CTRL, RM)                                                        \
    { int t_ = __builtin_amdgcn_update_dpp((int)0x80000000, x, CTRL, RM,       \
                                           0xF, false);                        \
      x = (x > t_) ? x : t_; }
    STEPM(0x111, 0xF) STEPM(0x112, 0xF) STEPM(0x114, 0xF)
    STEPM(0x118, 0xF) STEPM(0x142, 0xA) STEPM(0x143, 0xC)
#undef STEPM
    return __builtin_amdgcn_readlane(x, 63);
}

__global__ void __launch_bounds__(256)
fused_alpha_weights(const float* __restrict__ density,
                    const int*   __restrict__ ray_id,
                    const float* __restrict__ shift_p,
                    const float* __restrict__ interval_p,
                    float* __restrict__ weights,
                    float* __restrict__ alphainv,
                    int n_pts, int n_rays) {
    __shared__ float s_wv[4];
    __shared__ int   s_wf[4];
    __shared__ float s_red[4];
    __shared__ int   s_redi[4];

    const int t    = threadIdx.x;
    const int lane = t & 63;
    const int wid  = t >> 6;

    // XCD-aware bijective swizzle (m204): XCD k owns a contiguous data chunk,
    // so data-neighbor blocks are consecutive launches on the SAME XCD.
    const int nwg  = gridDim.x;
    const int orig = blockIdx.x;
    const int qq   = nwg / NXCD, rr = nwg % NXCD;
    const int xcd  = orig % NXCD;
    const int blk  = (xcd < rr ? xcd * (qq + 1) : rr * (qq + 1) + (xcd - rr) * qq)
                   + orig / NXCD;

    const int base = blk * BPTS;
    const int idx0 = base + t * EPT;

    const float shift = shift_p[0];
    const float c     = interval_p[0];
    const float sh2   = shift * LOG2E;
    const float negc  = -c;
    const bool  fast  = (c == 0.5f);

    // ================= phase 0: issue ALL loads up front =================
    int r[EPT + 1]; float d[EPT]; bool v[EPT];
    if (idx0 + EPT <= n_pts) {
        #pragma unroll
        for (int j = 0; j < EPT / 4; ++j) {
            const int4   ri = *reinterpret_cast<const int4*>(ray_id + idx0 + 4 * j);
            const float4 de = *reinterpret_cast<const float4*>(density + idx0 + 4 * j);
            r[4*j+0] = ri.x; r[4*j+1] = ri.y; r[4*j+2] = ri.z; r[4*j+3] = ri.w;
            d[4*j+0] = de.x; d[4*j+1] = de.y; d[4*j+2] = de.z; d[4*j+3] = de.w;
        }
        #pragma unroll
        for (int k = 0; k < EPT; ++k) v[k] = true;
    } else {
        #pragma unroll
        for (int k = 0; k < EPT; ++k) {
            const int i = idx0 + k;
            v[k] = (i < n_pts);
            r[k] = v[k] ? ray_id[i] : n_rays;    // sentinel past-end ray
            d[k] = v[k] ? density[i] : 0.0f;
        }
    }
    r[EPT] = (idx0 + EPT < n_pts) ? ray_id[idx0 + EPT] : n_rays;
    const int rprev = (idx0 == 0) ? -1
                    : ((idx0 <= n_pts) ? ray_id[idx0 - 1] : n_rays);

    int w_id = 0; float w_den = 0.0f; int rfirst = 0;
    if (base > 0) {                              // speculative lookback window
        const int wi = base - 256 + t;
        w_id   = ray_id[wi];
        w_den  = density[wi];
        rfirst = ray_id[base];                   // ray active at block head
    }

    // ================= phase 1: per-element values & flags =================
    float a[EPT]; int f[EPT];
    #pragma unroll
    for (int k = 0; k < EPT; ++k) {
        const float av = oma(d[k], sh2, negc, fast);
        a[k] = v[k] ? av : 1.0f;
        f[k] = (k == 0) ? (r[0] != rprev) : (r[k] != r[k - 1]);
    }

    // thread-local (V,F) fold over EPT elements
    float V = a[0];  int F = f[0];
    #pragma unroll
    for (int k = 1; k < EPT; ++k) {
        V = f[k] ? a[k] : V * a[k];
        F |= f[k];
    }

    // wave64 inclusive segmented scan (DPP, VALU-only)
    float Vi = V;  int Fi = F;
    seg_step<0x111, 0xF>(Vi, Fi);   // row_shr:1
    seg_step<0x112, 0xF>(Vi, Fi);   // row_shr:2
    seg_step<0x114, 0xF>(Vi, Fi);   // row_shr:4
    seg_step<0x118, 0xF>(Vi, Fi);   // row_shr:8
    seg_step<0x142, 0xA>(Vi, Fi);   // row_bcast:15 -> rows 1,3
    seg_step<0x143, 0xC>(Vi, Fi);   // row_bcast:31 -> rows 2,3

    // ================= phase 2: cross-wave + head carry (2 barriers) ======
    if (lane == 63) { s_wv[wid] = Vi; s_wf[wid] = Fi; }
    if (base > 0) {
        const int cand = (w_id != rfirst) ? t : -1;
        const int wm = wave_imax_bcast(cand);
        if (lane == 0) s_redi[wid] = wm;
    }
    __syncthreads();                             // barrier 1

    float carry0 = 1.0f;
    if (base > 0) {
        int m = s_redi[0];
        m = (s_redi[1] > m) ? s_redi[1] : m;
        m = (s_redi[2] > m) ? s_redi[2] : m;
        m = (s_redi[3] > m) ? s_redi[3] : m;
        // m >= 0: ray head at base-256+m+1; window product over (m, 256).
        float aa = oma(w_den, sh2, negc, fast);
        if (m >= 0 && t <= m) aa = 1.0f;
        const float wp = wave_prod_bcast(aa);
        if (lane == 0) s_red[wid] = wp;
        __syncthreads();                         // barrier 2
        carry0 = s_red[0] * s_red[1] * s_red[2] * s_red[3];

        if (m < 0) {                             // freak ray: walk further back
            int lo = base - 256;                 // [s0, lo) still missing
            int s0 = -1;
            while (s0 < 0) {
                const int wstart = lo - 256;
                const int i = wstart + t;
                const int vv = (i >= 0) ? ray_id[i] : -1;
                const int c2 = (vv != rfirst) ? t : -1;
                const int wm2 = wave_imax_bcast(c2);
                if (lane == 0) s_redi[wid] = wm2;
                __syncthreads();
                int m2 = s_redi[0];
                m2 = (s_redi[1] > m2) ? s_redi[1] : m2;
                m2 = (s_redi[2] > m2) ? s_redi[2] : m2;
                m2 = (s_redi[3] > m2) ? s_redi[3] : m2;
                __syncthreads();
                if (m2 >= 0) s0 = wstart + m2 + 1; else lo = wstart;
            }
            for (int off = s0; off < base - 256; off += 256) {
                const int i = off + t;
                const float aa2 = (i < base - 256)
                                ? oma(density[i], sh2, negc, fast) : 1.0f;
                const float wp2 = wave_prod_bcast(aa2);
                if (lane == 0) s_red[wid] = wp2;
                __syncthreads();
                carry0 *= s_red[0] * s_red[1] * s_red[2] * s_red[3];
                __syncthreads();
            }
        }
    }

    // exclusive pair for this thread (within wave)
    float Vx = __shfl_up(Vi, 1, 64);
    int   Fx = __shfl_up(Fi, 1, 64);
    if (lane == 0) { Vx = 1.0f; Fx = 0; }

    // fold block head carry + lower waves + lower lanes
    float Ev = carry0;
    #pragma unroll
    for (int w2 = 0; w2 < 3; ++w2) {
        if (w2 < wid) {
            const float bv = s_wv[w2];  const int bf = s_wf[w2];
            Ev = bf ? bv : Ev * bv;
        }
    }
    Ev = Fx ? Vx : Ev * Vx;            // exclusive transmittance at elem 0

    // ================= phase 3: T chain, weights, alphainv =================
    float T[EPT], e[EPT];
    float prev = Ev;
    #pragma unroll
    for (int k = 0; k < EPT; ++k) {
        T[k] = f[k] ? 1.0f : prev;
        e[k] = T[k] * a[k];
        prev = e[k];
    }

    if (idx0 + EPT <= n_pts) {
        #pragma unroll
        for (int j = 0; j < EPT / 4; ++j) {
            vf4 w = { T[4*j+0] - e[4*j+0], T[4*j+1] - e[4*j+1],
                      T[4*j+2] - e[4*j+2], T[4*j+3] - e[4*j+3] };
            __builtin_nontemporal_store(
                w, reinterpret_cast<vf4*>(weights + idx0 + 4 * j));
        }
    } else {
        #pragma unroll
        for (int k = 0; k < EPT; ++k)
            if (v[k]) weights[idx0 + k] = T[k] - e[k];
    }

    // segment ends: write alphainv for ending ray; fill empty rays in gaps
    #pragma unroll
    for (int k = 0; k < EPT; ++k) {
        if (v[k] && r[k] != r[k + 1]) {
            alphainv[r[k]] = e[k];
            for (int q = r[k] + 1; q < r[k + 1]; ++q) alphainv[q] = 1.0f;
        }
    }
    if (idx0 == 0) {                    // rays before the first point
        for (int q = 0; q < r[0]; ++q) alphainv[q] = 1.0f;
    }
}

extern "C" void kernel_launch(void* const* d_in, const int* in_sizes, int n_in,
                              void* d_out, int out_size, void* d_ws, size_t ws_size,
                              hipStream_t stream) {
    const float* density  = (const float*)d_in[0];
    const float* shift    = (const float*)d_in[1];   // 1-element array
    const float* interval = (const float*)d_in[2];   // 1-element array
    const int*   ray_id   = (const int*)d_in[3];
    const int n_pts  = in_sizes[0];
    const int n_rays = out_size - n_pts;

    float* weights  = (float*)d_out;              // [n_pts]
    float* alphainv = (float*)d_out + n_pts;      // [n_rays]

    const int grid = (n_pts + BPTS - 1) / BPTS;
    fused_alpha_weights<<<grid, 256, 0, stream>>>(
        density, ray_id, shift, interval, weights, alphainv, n_pts, n_rays);
}

// Round 13
// 24.102 us; speedup vs baseline: 1.3850x; 1.3850x over previous
//
#include <hip/hip_runtime.h>
#include <math.h>

// ---------------------------------------------------------------------------
// DirectVoxGO Raw2Alpha + Alphas2Weights (forward), single fused kernel.
//
// outputs (concatenated in d_out, float32):
//   weights[n_pts]         = alpha_j * T_j,  T_j = prod_{k<j} (1-alpha_k)
//   alphainv_last[n_rays]  = prod over ray of (1-alpha)  (empty rays -> 1.0)
//
// Structure: 1 block (512 thr) per 4096 consecutive points, 8 pts/thread
// (EPT=16 spills to scratch — R11 regression; EPT=8 fits in VGPRs).
// XCD-aware bijective block swizzle for L2 locality of the lookback.
// Neighbor ray-ids via LDS exchange (no extra global loads); thread 0's
// rprev comes from the lookback window's last element. 2 barriers/block.
// Segmented multiplicative scan: thread-local fold -> wave64 DPP (value,
// flag) scan -> 8-wave LDS combine -> local head-carry fold.
// ---------------------------------------------------------------------------

#define LOG2E 1.4426950408889634f
#define EPT   8                     // elements per thread (VGPR-safe)
#define NTHR  512                   // threads per block
#define BPTS  (NTHR * EPT)          // points per block = 4096
#define WIN   256                   // lookback window width
#define NXCD  8

typedef float vf4 __attribute__((ext_vector_type(4)));

__device__ __forceinline__ float exp2f_(float x) { return __builtin_amdgcn_exp2f(x); }
__device__ __forceinline__ float log2f_(float x) { return __builtin_amdgcn_logf(x); }
__device__ __forceinline__ float rsqf_(float x)  { return __builtin_amdgcn_rsqf(x); }

__device__ __forceinline__ float oma(float d, float sh2, float negc, bool fast) {
    const float y = fmaf(d, LOG2E, sh2);
    if (fast) return rsqf_(1.0f + exp2f_(y));
    const float sp = fmaxf(y, 0.f) + log2f_(1.f + exp2f_(-fabsf(y)));
    return exp2f_(negc * sp);
}

// Segmented-scan DPP step: combine src (earlier lanes, identity (1,0) when
// out-of-row/masked) into (V,F):  V = F ? V : Vs*V;  F |= Fs.
template <int CTRL, int RM>
__device__ __forceinline__ void seg_step(float& V, int& F) {
    const int vs_i = __builtin_amdgcn_update_dpp(
        0x3f800000, __builtin_bit_cast(int, V), CTRL, RM, 0xF, false);
    const int fs = __builtin_amdgcn_update_dpp(0, F, CTRL, RM, 0xF, false);
    const float vs = __builtin_bit_cast(float, vs_i);
    V = F ? V : vs * V;
    F = F | fs;
}

// Full-wave product, result broadcast to all lanes.
__device__ __forceinline__ float wave_prod_bcast(float x) {
#define STEPP(CTRL, RM)                                                        \
    { int t_ = __builtin_amdgcn_update_dpp(0x3f800000,                         \
          __builtin_bit_cast(int, x), CTRL, RM, 0xF, false);                   \
      x *= __builtin_bit_cast(float, t_); }
    STEPP(0x111, 0xF) STEPP(0x112, 0xF) STEPP(0x114, 0xF)
    STEPP(0x118, 0xF) STEPP(0x142, 0xA) STEPP(0x143, 0xC)
#undef STEPP
    return __builtin_bit_cast(float,
        __builtin_amdgcn_readlane(__builtin_bit_cast(int, x), 63));
}

// Full-wave int max, result broadcast to all lanes.
__device__ __forceinline__ int wave_imax_bcast(int x) {
#define STEPM(CTRL, RM)                                                        \
    { int t_ = __builtin_amdgcn_update_dpp((int)0x80000000, x, CTRL, RM,       \
                                           0xF, false);                        \
      x = (x > t_) ? x : t_; }
    STEPM(0x111, 0xF) STEPM(0x112, 0xF) STEPM(0x114, 0xF)
    STEPM(0x118, 0xF) STEPM(0x142, 0xA) STEPM(0x143, 0xC)
#undef STEPM
    return __builtin_amdgcn_readlane(x, 63);
}

__global__ void __launch_bounds__(NTHR)
fused_alpha_weights(const float* __restrict__ density,
                    const int*   __restrict__ ray_id,
                    const float* __restrict__ shift_p,
                    const float* __restrict__ interval_p,
                    float* __restrict__ weights,
                    float* __restrict__ alphainv,
                    int n_pts, int n_rays) {
    __shared__ int   s_first[NTHR];
    __shared__ int   s_last[NTHR];
    __shared__ float s_wv[8];
    __shared__ int   s_wf[8];
    __shared__ float s_red[8];
    __shared__ int   s_redi[8];
    __shared__ int   s_prevlast;     // ray_id[base-1]

    const int t    = threadIdx.x;
    const int lane = t & 63;
    const int wid  = t >> 6;         // 0..7

    // XCD-aware bijective swizzle (m204): XCD k owns a contiguous data chunk.
    const int nwg  = gridDim.x;
    const int orig = blockIdx.x;
    const int qq   = nwg / NXCD, rr = nwg % NXCD;
    const int xcd  = orig % NXCD;
    const int blk  = (xcd < rr ? xcd * (qq + 1) : rr * (qq + 1) + (xcd - rr) * qq)
                   + orig / NXCD;

    const int base = blk * BPTS;
    const int idx0 = base + t * EPT;

    const float shift = shift_p[0];
    const float c     = interval_p[0];
    const float sh2   = shift * LOG2E;
    const float negc  = -c;
    const bool  fast  = (c == 0.5f);

    // ================= phase 0: issue ALL loads up front =================
    int r[EPT + 1]; float d[EPT]; bool v[EPT];
    if (idx0 + EPT <= n_pts) {
        const int4   ri0 = *reinterpret_cast<const int4*>(ray_id + idx0);
        const int4   ri1 = *reinterpret_cast<const int4*>(ray_id + idx0 + 4);
        const float4 de0 = *reinterpret_cast<const float4*>(density + idx0);
        const float4 de1 = *reinterpret_cast<const float4*>(density + idx0 + 4);
        r[0] = ri0.x; r[1] = ri0.y; r[2] = ri0.z; r[3] = ri0.w;
        r[4] = ri1.x; r[5] = ri1.y; r[6] = ri1.z; r[7] = ri1.w;
        d[0] = de0.x; d[1] = de0.y; d[2] = de0.z; d[3] = de0.w;
        d[4] = de1.x; d[5] = de1.y; d[6] = de1.z; d[7] = de1.w;
        #pragma unroll
        for (int k = 0; k < EPT; ++k) v[k] = true;
    } else {
        #pragma unroll
        for (int k = 0; k < EPT; ++k) {
            const int i = idx0 + k;
            v[k] = (i < n_pts);
            r[k] = v[k] ? ray_id[i] : n_rays;    // sentinel past-end ray
            d[k] = v[k] ? density[i] : 0.0f;
        }
    }
    // only the last thread needs the id after the block's span
    int r8next = n_rays;
    if (t == NTHR - 1 && base + BPTS < n_pts) r8next = ray_id[base + BPTS];

    int w_id = 0; float w_den = 0.0f; int rfirst = 0;
    if (base > 0) {
        rfirst = ray_id[base];                   // ray active at block head
        if (t < WIN) {                           // speculative lookback window
            const int wi = base - WIN + t;
            w_id  = ray_id[wi];
            w_den = density[wi];
        }
    }

    // ================= phase A: LDS exchange + search reduce ==============
    s_first[t] = r[0];
    s_last[t]  = r[EPT - 1];
    if (base > 0 && t == WIN - 1) s_prevlast = w_id;   // ray_id[base-1]
    {
        const int cand = (base > 0 && t < WIN && w_id != rfirst) ? t : -1;
        const int wm = wave_imax_bcast(cand);
        if (lane == 0) s_redi[wid] = wm;
    }
    __syncthreads();                             // barrier A

    // neighbor ray ids from LDS (no extra global loads)
    const int rprev = (t > 0) ? s_last[t - 1]
                    : (base == 0 ? -1 : s_prevlast);
    r[EPT] = (t < NTHR - 1) ? s_first[t + 1] : r8next;

    int m = s_redi[0];
    #pragma unroll
    for (int w2 = 1; w2 < 8; ++w2) m = (s_redi[w2] > m) ? s_redi[w2] : m;

    // ================= phase 1: values, flags, fold, wave scan ============
    float a[EPT]; int f[EPT];
    #pragma unroll
    for (int k = 0; k < EPT; ++k) {
        const float av = oma(d[k], sh2, negc, fast);
        a[k] = v[k] ? av : 1.0f;
        f[k] = (k == 0) ? (r[0] != rprev) : (r[k] != r[k - 1]);
    }

    float V = a[0];  int F = f[0];
    #pragma unroll
    for (int k = 1; k < EPT; ++k) {
        V = f[k] ? a[k] : V * a[k];
        F |= f[k];
    }

    float Vi = V;  int Fi = F;
    seg_step<0x111, 0xF>(Vi, Fi);   // row_shr:1
    seg_step<0x112, 0xF>(Vi, Fi);   // row_shr:2
    seg_step<0x114, 0xF>(Vi, Fi);   // row_shr:4
    seg_step<0x118, 0xF>(Vi, Fi);   // row_shr:8
    seg_step<0x142, 0xA>(Vi, Fi);   // row_bcast:15 -> rows 1,3
    seg_step<0x143, 0xC>(Vi, Fi);   // row_bcast:31 -> rows 2,3

    // window partial product for the straddling ray's head
    if (base > 0) {
        float aa = 1.0f;
        if (t < WIN) {
            aa = oma(w_den, sh2, negc, fast);
            if (m >= 0 && t <= m) aa = 1.0f;     // before the ray's head
        }
        const float wp = wave_prod_bcast(aa);
        if (lane == 0) s_red[wid] = wp;
    }
    if (lane == 63) { s_wv[wid] = Vi; s_wf[wid] = Fi; }
    __syncthreads();                             // barrier B

    float carry0 = 1.0f;
    if (base > 0) {
        carry0 = s_red[0];
        #pragma unroll
        for (int w2 = 1; w2 < 8; ++w2) carry0 *= s_red[w2];

        if (m < 0) {                             // freak ray: walk further back
            int lo = base - WIN;                 // [s0, lo) still missing
            int s0 = -1;
            while (s0 < 0) {
                const int wstart = lo - WIN;
                int c2 = -1;
                if (t < WIN) {
                    const int i = wstart + t;
                    const int vv = (i >= 0) ? ray_id[i] : -1;
                    c2 = (vv != rfirst) ? t : -1;
                }
                const int wm2 = wave_imax_bcast(c2);
                if (lane == 0) s_redi[wid] = wm2;
                __syncthreads();
                int m2 = s_redi[0];
                #pragma unroll
                for (int w2 = 1; w2 < 8; ++w2)
                    m2 = (s_redi[w2] > m2) ? s_redi[w2] : m2;
                __syncthreads();
                if (m2 >= 0) s0 = wstart + m2 + 1; else lo = wstart;
            }
            for (int off = s0; off < base - WIN; off += WIN) {
                float aa2 = 1.0f;
                if (t < WIN) {
                    const int i = off + t;
                    if (i < base - WIN) aa2 = oma(density[i], sh2, negc, fast);
                }
                const float wp2 = wave_prod_bcast(aa2);
                if (lane == 0) s_red[wid] = wp2;
                __syncthreads();
                float pp = s_red[0];
                #pragma unroll
                for (int w2 = 1; w2 < 8; ++w2) pp *= s_red[w2];
                carry0 *= pp;
                __syncthreads();
            }
        }
    }

    // exclusive pair for this thread (within wave)
    float Vx = __shfl_up(Vi, 1, 64);
    int   Fx = __shfl_up(Fi, 1, 64);
    if (lane == 0) { Vx = 1.0f; Fx = 0; }

    // fold block head carry + lower waves + lower lanes
    float Ev = carry0;
    #pragma unroll
    for (int w2 = 0; w2 < 7; ++w2) {
        if (w2 < wid) {
            const float bv = s_wv[w2];  const int bf = s_wf[w2];
            Ev = bf ? bv : Ev * bv;
        }
    }
    Ev = Fx ? Vx : Ev * Vx;            // exclusive transmittance at elem 0

    // ================= phase 3: T chain, weights, alphainv =================
    float T[EPT], e[EPT];
    float prev = Ev;
    #pragma unroll
    for (int k = 0; k < EPT; ++k) {
        T[k] = f[k] ? 1.0f : prev;
        e[k] = T[k] * a[k];
        prev = e[k];
    }

    if (idx0 + EPT <= n_pts) {
        vf4 w0 = { T[0] - e[0], T[1] - e[1], T[2] - e[2], T[3] - e[3] };
        vf4 w1 = { T[4] - e[4], T[5] - e[5], T[6] - e[6], T[7] - e[7] };
        __builtin_nontemporal_store(w0, reinterpret_cast<vf4*>(weights + idx0));
        __builtin_nontemporal_store(w1, reinterpret_cast<vf4*>(weights + idx0 + 4));
    } else {
        #pragma unroll
        for (int k = 0; k < EPT; ++k)
            if (v[k]) weights[idx0 + k] = T[k] - e[k];
    }

    // segment ends: write alphainv for ending ray; fill empty rays in gaps
    #pragma unroll
    for (int k = 0; k < EPT; ++k) {
        if (v[k] && r[k] != r[k + 1]) {
            alphainv[r[k]] = e[k];
            for (int q = r[k] + 1; q < r[k + 1]; ++q) alphainv[q] = 1.0f;
        }
    }
    if (idx0 == 0) {                    // rays before the first point
        for (int q = 0; q < r[0]; ++q) alphainv[q] = 1.0f;
    }
}

extern "C" void kernel_launch(void* const* d_in, const int* in_sizes, int n_in,
                              void* d_out, int out_size, void* d_ws, size_t ws_size,
                              hipStream_t stream) {
    const float* density  = (const float*)d_in[0];
    const float* shift    = (const float*)d_in[1];   // 1-element array
    const float* interval = (const float*)d_in[2];   // 1-element array
    const int*   ray_id   = (const int*)d_in[3];
    const int n_pts  = in_sizes[0];
    const int n_rays = out_size - n_pts;

    float* weights  = (float*)d_out;              // [n_pts]
    float* alphainv = (float*)d_out + n_pts;      // [n_rays]

    const int grid = (n_pts + BPTS - 1) / BPTS;
    fused_alpha_weights<<<grid, NTHR, 0, stream>>>(
        density, ray_id, shift, interval, weights, alphainv, n_pts, n_rays);
}